// Round 2
// baseline (1361.985 us; speedup 1.0000x reference)
//
#include <hip/hip_runtime.h>

// VectorQuantizer — round 2: bf16 MFMA hi/lo-split GEMM + block-local argmin
// + exact-fp32 recheck for near-ties + separate memory-bound epilogue.
//
// score[k] = ||e_k||^2 - 2 * dot(x_p, e_k); dot via 3-term bf16 split:
//   x.e ~= (x_hi + x_lo).e_hi  +  x_hi.e_lo          (drop x_lo.e_lo ~1e-3)
// K' = 768: seg1 (512): A=(hi,lo) interleaved, B=(e_hi,e_hi) dup
//           seg2 (256): A=x_hi,               B=e_lo
// Pixels with (d2 - d1) < TAU are recomputed exactly in fp32 (round-1 math,
// which validated absmax==0 against the reference).

#define C_DIM   256
#define K_CODES 1024
#define HW      4096
#define BATCH   16
#define N_OUT   (BATCH * C_DIM * HW)
#define TAU     0.15f

typedef short bf16x8 __attribute__((ext_vector_type(8)));
typedef float f32x4  __attribute__((ext_vector_type(4)));

__device__ __forceinline__ unsigned short bf16_rne(float f) {
  unsigned b = __float_as_uint(f);
  b += 0x7FFFu + ((b >> 16) & 1u);
  return (unsigned short)(b >> 16);
}

__device__ __forceinline__ void gld16(const void* g, void* lds) {
#if __has_builtin(__builtin_amdgcn_global_load_lds)
  __builtin_amdgcn_global_load_lds(
      (const __attribute__((address_space(1))) unsigned int*)g,
      (__attribute__((address_space(3))) unsigned int*)lds, 16, 0, 0);
#else
  const int l = threadIdx.x & 63;
  ((int4*)lds)[l] = *(const int4*)((const char*)g);  // fallback (dst per-lane)
#endif
}

__global__ void k_zero(float* ws) { ws[0] = 0.f; }

// ---- prep: e2 (exact fp32), B1 = dup(e_hi) [1024][256 dw], B2 = e_lo [1024][128 dw]
__global__ __launch_bounds__(256) void k_prep(const float* __restrict__ emb,
                                              float* __restrict__ e2,
                                              unsigned int* __restrict__ B1,
                                              unsigned int* __restrict__ B2) {
  const int k = blockIdx.x * 256 + threadIdx.x;  // grid 4
  const float* er = emb + (size_t)k * C_DIM;
  unsigned int* b1r = B1 + (size_t)k * 256;
  unsigned int* b2r = B2 + (size_t)k * 128;
  float s = 0.f;
  unsigned prev = 0;
  for (int c = 0; c < C_DIM; ++c) {
    float v = er[c];
    s = fmaf(v, v, s);
    unsigned bb = __float_as_uint(v);
    unsigned hi = bb >> 16;
    float lo = v - __uint_as_float(bb & 0xFFFF0000u);
    unsigned los = bf16_rne(lo);
    b1r[c] = hi | (hi << 16);
    if (c & 1) b2r[c >> 1] = prev | (los << 16);
    else       prev = los;
  }
  e2[k] = s;
}

// ---- main: 512 blocks, each 128 pixels x all 1024 codes; writes idx|flag
__global__ __launch_bounds__(256, 2) void k_main(
    const float* __restrict__ x, const unsigned int* __restrict__ B1,
    const unsigned int* __restrict__ B2, const float* __restrict__ e2g,
    int* __restrict__ idxw) {
  __shared__ unsigned int As[128 * 32];   // 16 KB : 128 rows x 8 quads (swizzled)
  __shared__ unsigned int Bs[256 * 32];   // 32 KB : 256 rows x 8 quads (swizzled)
  __shared__ float e2s[K_CODES];          // 4 KB
  __shared__ float fin_d1[2][128], fin_d2[2][128];
  __shared__ int   fin_i1[2][128];

  const int t   = threadIdx.x;
  const int blk = blockIdx.x;            // 512 = 16 b * 32
  const int b   = blk >> 5;
  const int p0  = (blk & 31) << 7;
  const float* xb = x + ((size_t)b << 20) + p0;

  const int wv = t >> 6, l = t & 63;
  const int wm = wv >> 1, wn = wv & 1;
  const int l15 = l & 15, l4 = l >> 4, s7 = l15 & 7;

#pragma unroll
  for (int i = 0; i < 4; ++i) e2s[t + 256 * i] = e2g[t + 256 * i];
  if (t < 128) {
    fin_d1[0][t] = 1e30f; fin_d2[0][t] = 1e30f; fin_i1[0][t] = 0;
    fin_d1[1][t] = 1e30f; fin_d2[1][t] = 1e30f; fin_i1[1][t] = 0;
  }

  const int rb_lane = (wv << 6) + (l >> 3);
  const int swz16   = (((l & 7) ^ ((l >> 3) & 7)) << 4);
  const short* AsS = (const short*)As;
  const short* BsS = (const short*)Bs;

  f32x4 acc[4][8];
  for (int iter = 0; iter < 4; ++iter) {
    const int nbase = iter << 8;
#pragma unroll
    for (int mi = 0; mi < 4; ++mi)
#pragma unroll
      for (int ni = 0; ni < 8; ++ni) acc[mi][ni] = (f32x4){0.f, 0.f, 0.f, 0.f};

    const char* b1lane = (const char*)B1 + (((size_t)(nbase + rb_lane)) << 10) + swz16;
    const char* b2lane = (const char*)B2 + (((size_t)(nbase + rb_lane)) << 9) + swz16;

    for (int j = 0; j < 4; ++j) {
#pragma unroll
      for (int sub = 0; sub < 3; ++sub) {
        __syncthreads();
        // ---------- B staging: async global->LDS, pre-swizzled addressing ----
        if (sub < 2) {
          const char* src = b1lane + ((2 * j + sub) << 7);
#pragma unroll
          for (int il = 0; il < 8; ++il)
            gld16(src + (il << 13), (void*)&Bs[(((wv << 6) + (il << 3))) << 5]);
        } else {
          const char* src = b2lane + (j << 7);
#pragma unroll
          for (int il = 0; il < 8; ++il)
            gld16(src + (il << 12), (void*)&Bs[(((wv << 6) + (il << 3))) << 5]);
        }
        // ---------- A staging: fp32 -> (hi,lo)/(hi,hi') bf16, swizzled LDS ---
        if (sub < 2) {
          const int c0 = (2 * j + sub) << 5;
#pragma unroll
          for (int i = 0; i < 16; ++i) {
            int id = (i << 8) + t;
            int cr = id >> 7, p = id & 127;
            float v = xb[(size_t)(c0 + cr) * HW + p];
            unsigned bb = __float_as_uint(v);
            unsigned hi = bb >> 16;
            float lo = v - __uint_as_float(bb & 0xFFFF0000u);
            unsigned d = hi | ((unsigned)bf16_rne(lo) << 16);
            As[(p << 5) + ((((cr >> 2) ^ (p & 7)) << 2) | (cr & 3))] = d;
          }
        } else {
          const int c0 = j << 6;
#pragma unroll
          for (int i = 0; i < 16; ++i) {
            int id = (i << 8) + t;
            int cp = id >> 7, p = id & 127;
            float v0 = xb[(size_t)(c0 + 2 * cp) * HW + p];
            float v1 = xb[(size_t)(c0 + 2 * cp + 1) * HW + p];
            unsigned d = (__float_as_uint(v0) >> 16) | ((__float_as_uint(v1) >> 16) << 16);
            As[(p << 5) + ((((cp >> 2) ^ (p & 7)) << 2) | (cp & 3))] = d;
          }
        }
        __syncthreads();
        // ---------- compute: 2 k-steps of 32 ------------------------------
#pragma unroll
        for (int ks = 0; ks < 2; ++ks) {
          const int sw = ((ks << 2) + l4) ^ s7;
          bf16x8 af[4], bfr[8];
#pragma unroll
          for (int mi = 0; mi < 4; ++mi) {
            int q = ((wm << 6) + (mi << 4) + l15) * 8 + sw;
            af[mi] = *(const bf16x8*)(AsS + (q << 3));
          }
#pragma unroll
          for (int ni = 0; ni < 8; ++ni) {
            int q = ((wn << 7) + (ni << 4) + l15) * 8 + sw;
            bfr[ni] = *(const bf16x8*)(BsS + (q << 3));
          }
#pragma unroll
          for (int mi = 0; mi < 4; ++mi)
#pragma unroll
            for (int ni = 0; ni < 8; ++ni)
              acc[mi][ni] = __builtin_amdgcn_mfma_f32_16x16x32_bf16(
                  af[mi], bfr[ni], acc[mi][ni], 0, 0, 0);
        }
      }
    }
    // ---------- iter epilogue: scores -> per-pixel top2 ----------------------
    float e2v[8];
#pragma unroll
    for (int ni = 0; ni < 8; ++ni) e2v[ni] = e2s[nbase + (wn << 7) + (ni << 4) + l15];
    const int cbase = nbase + (wn << 7) + l15;
#pragma unroll
    for (int mi = 0; mi < 4; ++mi) {
#pragma unroll
      for (int r = 0; r < 4; ++r) {
        float d1 = 1e30f, d2 = 1e30f;
        int i1 = 0;
#pragma unroll
        for (int ni = 0; ni < 8; ++ni) {
          float s = fmaf(-2.f, acc[mi][ni][r], e2v[ni]);
          int c = cbase + (ni << 4);
          bool lt = s < d1;
          d2 = lt ? d1 : (s < d2 ? s : d2);
          d1 = lt ? s : d1;
          i1 = lt ? c : i1;
        }
#pragma unroll
        for (int m = 1; m < 16; m <<= 1) {
          float od1 = __shfl_xor(d1, m);
          float od2 = __shfl_xor(d2, m);
          int   oi1 = __shfl_xor(i1, m);
          bool take = (od1 < d1) || (od1 == d1 && oi1 < i1);
          float loser = take ? d1 : od1;
          d2 = fminf(fminf(d2, od2), loser);
          d1 = take ? od1 : d1;
          i1 = take ? oi1 : i1;
        }
        if (l15 == 0) {
          int px = (wm << 6) + (mi << 4) + (l4 << 2) + r;
          float fd1 = fin_d1[wn][px], fd2 = fin_d2[wn][px];
          int   fi1 = fin_i1[wn][px];
          bool take = (d1 < fd1) || (d1 == fd1 && i1 < fi1);
          float loser = take ? fd1 : d1;
          fin_d2[wn][px] = fminf(fminf(fd2, d2), loser);
          fin_d1[wn][px] = take ? d1 : fd1;
          fin_i1[wn][px] = take ? i1 : fi1;
        }
      }
    }
  }
  __syncthreads();
  if (t < 128) {
    float a1 = fin_d1[0][t], a2 = fin_d2[0][t];
    int   ai = fin_i1[0][t];
    float c1 = fin_d1[1][t], c2 = fin_d2[1][t];
    int   ci = fin_i1[1][t];
    bool take = (c1 < a1) || (c1 == a1 && ci < ai);
    float d1 = take ? c1 : a1;
    int   i1 = take ? ci : ai;
    float d2 = fminf(fminf(a2, c2), take ? a1 : c1);
    int flag = (d2 - d1 < TAU) ? (1 << 30) : 0;
    idxw[((size_t)b << 12) + p0 + t] = i1 | flag;
  }
}

// ---- exact fp32 recheck for flagged pixels (round-1-validated math) --------
__global__ __launch_bounds__(256) void k_recheck(const float* __restrict__ x,
                                                 const float* __restrict__ emb,
                                                 const float* __restrict__ e2,
                                                 int* __restrict__ idxw) {
  __shared__ int list[1024];
  __shared__ int cnt;
  __shared__ float rd[4];
  __shared__ int   ri[4];
  const int t = threadIdx.x;
  const int base = blockIdx.x * 1024;    // 64 blocks
  if (t == 0) cnt = 0;
  __syncthreads();
  for (int i = 0; i < 4; ++i) {
    int gp = base + i * 256 + t;
    if (idxw[gp] & (1 << 30)) list[atomicAdd(&cnt, 1)] = gp;
  }
  __syncthreads();
  const int n = cnt;
  for (int ii = 0; ii < n; ++ii) {
    const int gp = list[ii];
    const int bb = gp >> 12, p = gp & 4095;
    const float* xp = x + ((size_t)bb << 20) + p;
    const float* e0 = emb + (size_t)(4 * t) * C_DIM;
    float s0 = 0.f, s1 = 0.f, s2 = 0.f, s3 = 0.f;
    for (int c = 0; c < C_DIM; ++c) {
      float xv = xp[(size_t)c << 12];
      s0 = fmaf(xv, e0[c], s0);
      s1 = fmaf(xv, e0[C_DIM + c], s1);
      s2 = fmaf(xv, e0[2 * C_DIM + c], s2);
      s3 = fmaf(xv, e0[3 * C_DIM + c], s3);
    }
    float bd = e2[4 * t] - 2.f * s0;
    int   bk = 4 * t;
    float dv;
    dv = e2[4 * t + 1] - 2.f * s1; if (dv < bd) { bd = dv; bk = 4 * t + 1; }
    dv = e2[4 * t + 2] - 2.f * s2; if (dv < bd) { bd = dv; bk = 4 * t + 2; }
    dv = e2[4 * t + 3] - 2.f * s3; if (dv < bd) { bd = dv; bk = 4 * t + 3; }
#pragma unroll
    for (int m = 1; m < 64; m <<= 1) {
      float od = __shfl_xor(bd, m);
      int   oi = __shfl_xor(bk, m);
      if (od < bd || (od == bd && oi < bk)) { bd = od; bk = oi; }
    }
    if ((t & 63) == 0) { rd[t >> 6] = bd; ri[t >> 6] = bk; }
    __syncthreads();
    if (t == 0) {
      for (int w = 1; w < 4; ++w)
        if (rd[w] < bd || (rd[w] == bd && ri[w] < bk)) { bd = rd[w]; bk = ri[w]; }
      idxw[gp] = bk;
    }
    __syncthreads();
  }
}

// ---- epilogue: gather + transposed store + loss (round-1 verified) ---------
__global__ __launch_bounds__(256) void k_epi(const float* __restrict__ x,
                                             const float* __restrict__ emb,
                                             const int* __restrict__ idxw,
                                             float* __restrict__ out,
                                             float* __restrict__ loss_acc) {
  __shared__ int bidx_s[64];
  __shared__ float lred[4];
  const int t = threadIdx.x;
  const int tile = blockIdx.x;           // 1024 = 16 b * 64
  const int b = tile >> 6, p0 = (tile & 63) << 6;
  const float* xb = x + ((size_t)b << 20) + p0;
  float* outb = out + ((size_t)b << 20) + p0;
  if (t < 64) bidx_s[t] = idxw[((size_t)b << 12) + p0 + t] & 1023;
  __syncthreads();
  float lsum = 0.f;
#pragma unroll 4
  for (int i = 0; i < 16; ++i) {
    int fidx = t + 256 * i;
    int c = fidx >> 4, p4 = (fidx & 15) << 2;
    const float4 x4 = *(const float4*)&xb[((size_t)c << 12) + p4];
    const int j0 = bidx_s[p4], j1 = bidx_s[p4 + 1], j2 = bidx_s[p4 + 2], j3 = bidx_s[p4 + 3];
    const float q0 = emb[(size_t)j0 * C_DIM + c];
    const float q1 = emb[(size_t)j1 * C_DIM + c];
    const float q2 = emb[(size_t)j2 * C_DIM + c];
    const float q3 = emb[(size_t)j3 * C_DIM + c];
    const float d0 = q0 - x4.x, d1 = q1 - x4.y, d2 = q2 - x4.z, d3 = q3 - x4.w;
    lsum += d0 * d0 + d1 * d1 + d2 * d2 + d3 * d3;
    float4 o; o.x = q0; o.y = q1; o.z = q2; o.w = q3;
    *(float4*)&outb[((size_t)c << 12) + p4] = o;
  }
  for (int off = 32; off > 0; off >>= 1) lsum += __shfl_down(lsum, off, 64);
  if ((t & 63) == 0) lred[t >> 6] = lsum;
  __syncthreads();
  if (t == 0) atomicAdd(loss_acc, lred[0] + lred[1] + lred[2] + lred[3]);
}

__global__ void k_final(const float* __restrict__ ws, float* __restrict__ out) {
  out[N_OUT] = 2.0f * ws[0] / (float)N_OUT;
}

// ================= round-1 fp32 fallback (ws too small) =====================
__global__ __launch_bounds__(256) void k_e2f(const float* __restrict__ emb,
                                             float* __restrict__ e2) {
  int k = blockIdx.x * 256 + threadIdx.x;
  const float* e = emb + (size_t)k * C_DIM;
  float s = 0.f;
#pragma unroll 8
  for (int c = 0; c < C_DIM; ++c) s += e[c] * e[c];
  e2[k] = s;
}

__global__ __launch_bounds__(256, 4) void k_main_r1(
    const float* __restrict__ x, const float* __restrict__ emb,
    const float* __restrict__ e2, float* __restrict__ out,
    float* __restrict__ loss_acc) {
  __shared__ float smem[64 * 64 + 64 * 64];
  float* xs = smem;
  float* es = smem + 64 * 64;
  float* red_d = smem;
  int* red_i = (int*)(smem + 64 * 16);
  int* bidx_s = (int*)(smem + 64 * 32);
  float* lred = smem + 64 * 32 + 64;
  const int t = threadIdx.x;
  const int tile = blockIdx.x;
  const int b = tile >> 6;
  const int p0 = (tile & 63) << 6;
  const float* xb = x + (size_t)b * C_DIM * HW + p0;
  const int pg = t & 15, kg = t >> 4;
  float best0 = 1e30f, best1 = 1e30f, best2 = 1e30f, best3 = 1e30f;
  int bi0 = 0, bi1 = 0, bi2 = 0, bi3 = 0;
  for (int kc = 0; kc < 16; ++kc) {
    const int k0 = kc * 64;
    float a00 = 0, a01 = 0, a02 = 0, a03 = 0, a10 = 0, a11 = 0, a12 = 0, a13 = 0;
    float a20 = 0, a21 = 0, a22 = 0, a23 = 0, a30 = 0, a31 = 0, a32 = 0, a33 = 0;
    for (int cs0 = 0; cs0 < 4; ++cs0) {
      __syncthreads();
#pragma unroll
      for (int i = 0; i < 4; ++i) {
        int fidx = t + 256 * i;
        int cs = fidx >> 4, p4 = (fidx & 15) << 2;
        *(float4*)&xs[cs * 64 + p4] = *(const float4*)&xb[(size_t)(cs0 * 64 + cs) * HW + p4];
      }
      for (int i = 0; i < 16; ++i) {
        int idx2 = t + 256 * i;
        int cs = idx2 >> 6, kk = idx2 & 63;
        es[cs * 64 + kk] = emb[(size_t)(k0 + kk) * C_DIM + cs0 * 64 + cs];
      }
      __syncthreads();
#pragma unroll 8
      for (int cs = 0; cs < 64; ++cs) {
        const float4 xv = *(const float4*)&xs[cs * 64 + (pg << 2)];
        const float4 ev = *(const float4*)&es[cs * 64 + (kg << 2)];
        a00 += xv.x * ev.x; a01 += xv.x * ev.y; a02 += xv.x * ev.z; a03 += xv.x * ev.w;
        a10 += xv.y * ev.x; a11 += xv.y * ev.y; a12 += xv.y * ev.z; a13 += xv.y * ev.w;
        a20 += xv.z * ev.x; a21 += xv.z * ev.y; a22 += xv.z * ev.z; a23 += xv.z * ev.w;
        a30 += xv.w * ev.x; a31 += xv.w * ev.y; a32 += xv.w * ev.z; a33 += xv.w * ev.w;
      }
    }
    const int kb = k0 + (kg << 2);
    const float e20 = e2[kb], e21 = e2[kb + 1], e22 = e2[kb + 2], e23 = e2[kb + 3];
    float s;
    s = e20 - 2.f * a00; if (s < best0) { best0 = s; bi0 = kb; }
    s = e21 - 2.f * a01; if (s < best0) { best0 = s; bi0 = kb + 1; }
    s = e22 - 2.f * a02; if (s < best0) { best0 = s; bi0 = kb + 2; }
    s = e23 - 2.f * a03; if (s < best0) { best0 = s; bi0 = kb + 3; }
    s = e20 - 2.f * a10; if (s < best1) { best1 = s; bi1 = kb; }
    s = e21 - 2.f * a11; if (s < best1) { best1 = s; bi1 = kb + 1; }
    s = e22 - 2.f * a12; if (s < best1) { best1 = s; bi1 = kb + 2; }
    s = e23 - 2.f * a13; if (s < best1) { best1 = s; bi1 = kb + 3; }
    s = e20 - 2.f * a20; if (s < best2) { best2 = s; bi2 = kb; }
    s = e21 - 2.f * a21; if (s < best2) { best2 = s; bi2 = kb + 1; }
    s = e22 - 2.f * a22; if (s < best2) { best2 = s; bi2 = kb + 2; }
    s = e23 - 2.f * a23; if (s < best2) { best2 = s; bi2 = kb + 3; }
    s = e20 - 2.f * a30; if (s < best3) { best3 = s; bi3 = kb; }
    s = e21 - 2.f * a31; if (s < best3) { best3 = s; bi3 = kb + 1; }
    s = e22 - 2.f * a32; if (s < best3) { best3 = s; bi3 = kb + 2; }
    s = e23 - 2.f * a33; if (s < best3) { best3 = s; bi3 = kb + 3; }
  }
  __syncthreads();
  const int prow = pg << 2;
  red_d[(prow + 0) * 16 + kg] = best0; red_i[(prow + 0) * 16 + kg] = bi0;
  red_d[(prow + 1) * 16 + kg] = best1; red_i[(prow + 1) * 16 + kg] = bi1;
  red_d[(prow + 2) * 16 + kg] = best2; red_i[(prow + 2) * 16 + kg] = bi2;
  red_d[(prow + 3) * 16 + kg] = best3; red_i[(prow + 3) * 16 + kg] = bi3;
  __syncthreads();
  if (t < 64) {
    float bd = red_d[t * 16];
    int bk = red_i[t * 16];
    for (int g = 1; g < 16; ++g) {
      float d = red_d[t * 16 + g];
      int k = red_i[t * 16 + g];
      if (d < bd || (d == bd && k < bk)) { bd = d; bk = k; }
    }
    bidx_s[t] = bk;
  }
  __syncthreads();
  float lsum = 0.f;
  float* outb = out + (size_t)b * C_DIM * HW + p0;
#pragma unroll 4
  for (int i = 0; i < 16; ++i) {
    int fidx = t + 256 * i;
    int c = fidx >> 4, p4 = (fidx & 15) << 2;
    const float4 x4 = *(const float4*)&xb[(size_t)c * HW + p4];
    const int j0 = bidx_s[p4], j1 = bidx_s[p4 + 1], j2 = bidx_s[p4 + 2], j3 = bidx_s[p4 + 3];
    const float q0 = emb[(size_t)j0 * C_DIM + c];
    const float q1 = emb[(size_t)j1 * C_DIM + c];
    const float q2 = emb[(size_t)j2 * C_DIM + c];
    const float q3 = emb[(size_t)j3 * C_DIM + c];
    const float d0 = q0 - x4.x, d1 = q1 - x4.y, d2 = q2 - x4.z, d3 = q3 - x4.w;
    lsum += d0 * d0 + d1 * d1 + d2 * d2 + d3 * d3;
    float4 o; o.x = q0; o.y = q1; o.z = q2; o.w = q3;
    *(float4*)&outb[(size_t)c * HW + p4] = o;
  }
  for (int off = 32; off > 0; off >>= 1) lsum += __shfl_down(lsum, off, 64);
  if ((t & 63) == 0) lred[t >> 6] = lsum;
  __syncthreads();
  if (t == 0) atomicAdd(loss_acc, lred[0] + lred[1] + lred[2] + lred[3]);
}

// ============================================================================
extern "C" void kernel_launch(void* const* d_in, const int* in_sizes, int n_in,
                              void* d_out, int out_size, void* d_ws, size_t ws_size,
                              hipStream_t stream) {
  const float* x = (const float*)d_in[0];
  const float* emb = (const float*)d_in[1];
  float* out = (float*)d_out;
  char* ws = (char*)d_ws;

  // ws layout (bytes): 0 loss | 256 e2 (4 KB) | 8192 idx (256 KB)
  //                    | 270336 B1 (1 MB) | 1318912 B2 (512 KB) | end 1843200
  const size_t NEED = 1843200;
  if (ws_size >= NEED) {
    float* lossp = (float*)ws;
    float* e2 = (float*)(ws + 256);
    int* idx = (int*)(ws + 8192);
    unsigned int* B1 = (unsigned int*)(ws + 270336);
    unsigned int* B2 = (unsigned int*)(ws + 1318912);
    k_zero<<<1, 1, 0, stream>>>(lossp);
    k_prep<<<4, 256, 0, stream>>>(emb, e2, B1, B2);
    k_main<<<512, 256, 0, stream>>>(x, B1, B2, e2, idx);
    k_recheck<<<64, 256, 0, stream>>>(x, emb, e2, idx);
    k_epi<<<1024, 256, 0, stream>>>(x, emb, idx, out, lossp);
    k_final<<<1, 1, 0, stream>>>(lossp, out);
  } else {
    // round-1 fp32 fallback (needs only ~4.3 KB of ws)
    float* wsf = (float*)ws;
    float* e2 = wsf + 64;
    k_zero<<<1, 1, 0, stream>>>(wsf);
    k_e2f<<<K_CODES / 256, 256, 0, stream>>>(emb, e2);
    k_main_r1<<<1024, 256, 0, stream>>>(x, emb, e2, out, wsf);
    k_final<<<1, 1, 0, stream>>>(wsf, out);
  }
}

// Round 3
// 281.994 us; speedup vs baseline: 4.8298x; 4.8298x over previous
//
#include <hip/hip_runtime.h>
#include <hip/hip_fp16.h>

// VectorQuantizer — round 3: fp16 (RNE) single-term MFMA GEMM, A-in-registers,
// fragment-ordered B prepack + coalesced gld16 staging, register top-2,
// list-based parallel exact-fp32 recheck (8 px per block share codebook sweep).
//
// score[k] = ||e_k||^2 - 2 * dot(fp16(x), fp16(e_k))   [fp32 MFMA accum]
// max |score err| ~0.05  =>  flag near-ties with TAU=0.25, exact-recheck them.

#define C_DIM   256
#define K_CODES 1024
#define HW      4096
#define N_OUT   (16 * C_DIM * HW)
#define TAU     0.25f
#define LISTCAP 16384
#define RPP     8
#define RGRID   512

typedef _Float16 f16x8 __attribute__((ext_vector_type(8)));
typedef float    f32x4 __attribute__((ext_vector_type(4)));
typedef unsigned u32x4 __attribute__((ext_vector_type(4)));

__device__ __forceinline__ void gld16(const void* g, void* lds) {
#if __has_builtin(__builtin_amdgcn_global_load_lds)
  __builtin_amdgcn_global_load_lds(
      (const __attribute__((address_space(1))) unsigned int*)g,
      (__attribute__((address_space(3))) unsigned int*)lds, 16, 0, 0);
#else
  ((int4*)lds)[threadIdx.x & 63] = *(const int4*)g;
#endif
}

__global__ void k_zero(float* ws) { ws[0] = 0.f; ((int*)ws)[1] = 0; }

// ---- e2[k] = ||e_k||^2, one wave per code --------------------------------
__global__ __launch_bounds__(256) void k_e2(const float* __restrict__ emb,
                                            float* __restrict__ e2) {
  const int t = threadIdx.x, w = t >> 6, l = t & 63;
  const int k = blockIdx.x * 4 + w;               // grid 256
  const float4 v = *(const float4*)(emb + (size_t)k * C_DIM + l * 4);
  float s = v.x * v.x + v.y * v.y + v.z * v.z + v.w * v.w;
  for (int m = 32; m; m >>= 1) s += __shfl_down(s, m, 64);
  if (l == 0) e2[k] = s;
}

// ---- B prepack: fp16(emb) in MFMA-fragment order -------------------------
// slot s in [0,32768): l=s&63, ks=(s>>6)&7, ni=(s>>9)&7, cb=s>>12
// code n = cb*128 + ni*16 + (l&15);  c0 = ks*32 + (l>>4)*8;  4 dwords = 8 c's
__global__ __launch_bounds__(256) void k_prep(const float* __restrict__ emb,
                                              unsigned* __restrict__ Bp) {
  const int s = blockIdx.x * 256 + threadIdx.x;   // grid 128
  const int l = s & 63, ks = (s >> 6) & 7, ni = (s >> 9) & 7, cb = s >> 12;
  const int n = (cb << 7) + (ni << 4) + (l & 15);
  const int c0 = (ks << 5) + ((l >> 4) << 3);
  const float* er = emb + (size_t)n * C_DIM + c0;
  u32x4 out;
#pragma unroll
  for (int d = 0; d < 4; ++d) {
    __half2 h = __floats2half2_rn(er[2 * d], er[2 * d + 1]);
    out[d] = *(unsigned*)&h;
  }
  *(u32x4*)(Bp + (size_t)s * 4) = out;
}

// ---- main: 512 blocks x 128 px; wave = 32 px, all 1024 codes -------------
__global__ __launch_bounds__(256, 2) void k_main(
    const float* __restrict__ x, const unsigned* __restrict__ Bp,
    const float* __restrict__ e2g, int* __restrict__ idxw,
    int* __restrict__ list, int* __restrict__ cntp) {
  __shared__ unsigned Bs[64 * 256];   // 64 KB: [tile=ni*8+ks][lane*4 dw]
  __shared__ float e2s[K_CODES];      // 4 KB

  const int t = threadIdx.x;
  const int w = t >> 6, l = t & 63;
  const int l15 = l & 15, l4 = l >> 4;
  const int blk = blockIdx.x;         // 512 = 16 b * 32 tiles
  const int b = blk >> 5;
  const int p0 = (blk & 31) << 7;
  const int pxw = p0 + (w << 5);      // wave's 32-pixel base

#pragma unroll
  for (int i = 0; i < 4; ++i) e2s[t + 256 * i] = e2g[t + 256 * i];

  // A fragments: 2 mi x 8 ksteps, converted once, live in registers all kernel
  const float* xb = x + ((size_t)b << 20);
  u32x4 afu[2][8];
#pragma unroll
  for (int mi = 0; mi < 2; ++mi) {
    const int px = pxw + (mi << 4) + l15;
#pragma unroll
    for (int ks = 0; ks < 8; ++ks) {
#pragma unroll
      for (int d = 0; d < 4; ++d) {
        const int c = (ks << 5) + (l4 << 3) + (d << 1);
        const float v0 = xb[((size_t)c << 12) + px];
        const float v1 = xb[((size_t)(c + 1) << 12) + px];
        __half2 h = __floats2half2_rn(v0, v1);
        afu[mi][ks][d] = *(unsigned*)&h;
      }
    }
  }

  float d1[2][4], d2v[2][4];
  int   i1[2][4];
#pragma unroll
  for (int mi = 0; mi < 2; ++mi)
#pragma unroll
    for (int r = 0; r < 4; ++r) { d1[mi][r] = 1e30f; d2v[mi][r] = 1e30f; i1[mi][r] = 0; }

  for (int cb = 0; cb < 8; ++cb) {
    __syncthreads();                            // prev-pass consumers done
    const unsigned* src0 = Bp + ((size_t)cb << 14);
#pragma unroll
    for (int i = 0; i < 16; ++i) {
      const int tile = (w << 4) + i;
      gld16(src0 + (tile << 8) + (l << 2), (void*)&Bs[tile << 8]);
    }
    __syncthreads();                            // staged data visible

    f32x4 acc[2][8];
#pragma unroll
    for (int mi = 0; mi < 2; ++mi)
#pragma unroll
      for (int ni = 0; ni < 8; ++ni) acc[mi][ni] = (f32x4){0.f, 0.f, 0.f, 0.f};

#pragma unroll
    for (int ks = 0; ks < 8; ++ks) {
      const f16x8 a0 = __builtin_bit_cast(f16x8, afu[0][ks]);
      const f16x8 a1 = __builtin_bit_cast(f16x8, afu[1][ks]);
#pragma unroll
      for (int ni = 0; ni < 8; ++ni) {
        const f16x8 bf = __builtin_bit_cast(
            f16x8, *(const u32x4*)&Bs[(((ni << 3) + ks) << 8) + (l << 2)]);
        acc[0][ni] = __builtin_amdgcn_mfma_f32_16x16x32_f16(a0, bf, acc[0][ni], 0, 0, 0);
        acc[1][ni] = __builtin_amdgcn_mfma_f32_16x16x32_f16(a1, bf, acc[1][ni], 0, 0, 0);
      }
    }

    // per-pass top-2 (codes cb*128 + ni*16 + l15), merge into register state
    const int cb128 = cb << 7;
    float e2v[8];
#pragma unroll
    for (int ni = 0; ni < 8; ++ni) e2v[ni] = e2s[cb128 + (ni << 4) + l15];
#pragma unroll
    for (int mi = 0; mi < 2; ++mi) {
#pragma unroll
      for (int r = 0; r < 4; ++r) {
        float pd1 = 1e30f, pd2 = 1e30f;
        int   pi1 = 0;
#pragma unroll
        for (int ni = 0; ni < 8; ++ni) {
          const float s = fmaf(-2.f, acc[mi][ni][r], e2v[ni]);
          const int c = cb128 + (ni << 4) + l15;
          const bool lt = s < pd1;
          pd2 = lt ? pd1 : (s < pd2 ? s : pd2);
          pi1 = lt ? c : pi1;
          pd1 = lt ? s : pd1;
        }
#pragma unroll
        for (int m = 1; m < 16; m <<= 1) {
          const float od1 = __shfl_xor(pd1, m);
          const float od2 = __shfl_xor(pd2, m);
          const int   oi1 = __shfl_xor(pi1, m);
          const bool take = (od1 < pd1) || (od1 == pd1 && oi1 < pi1);
          const float loser = take ? pd1 : od1;
          pd2 = fminf(fminf(pd2, od2), loser);
          pd1 = take ? od1 : pd1;
          pi1 = take ? oi1 : pi1;
        }
        const bool take = (pd1 < d1[mi][r]) || (pd1 == d1[mi][r] && pi1 < i1[mi][r]);
        const float loser = take ? d1[mi][r] : pd1;
        d2v[mi][r] = fminf(fminf(d2v[mi][r], pd2), loser);
        d1[mi][r] = take ? pd1 : d1[mi][r];
        i1[mi][r] = take ? pi1 : i1[mi][r];
      }
    }
  }

  if (l15 == 0) {
#pragma unroll
    for (int mi = 0; mi < 2; ++mi)
#pragma unroll
      for (int r = 0; r < 4; ++r) {
        const int px = pxw + (mi << 4) + (l4 << 2) + r;
        const int gp = (b << 12) + px;
        idxw[gp] = i1[mi][r];
        if (d2v[mi][r] - d1[mi][r] < TAU) {
          const int pos = atomicAdd(cntp, 1);
          if (pos < LISTCAP) list[pos] = gp;
        }
      }
  }
}

// ---- exact fp32 recheck: 8 flagged pixels per block share codebook sweep --
__global__ __launch_bounds__(256) void k_recheck(
    const float* __restrict__ x, const float* __restrict__ emb,
    const float* __restrict__ e2, const int* __restrict__ list,
    const int* __restrict__ cntp, int* __restrict__ idxw) {
  __shared__ float xs[RPP][C_DIM];   // 8 KB
  __shared__ int   gps[RPP];
  __shared__ float wbest[RPP][4];
  __shared__ int   wbidx[RPP][4];
  const int t = threadIdx.x;
  const int cnt = min(*cntp, LISTCAP);
  float e2l[4];
#pragma unroll
  for (int j = 0; j < 4; ++j) e2l[j] = e2[t * 4 + j];

  for (int base = blockIdx.x * RPP; base < cnt; base += RGRID * RPP) {
    __syncthreads();
    if (t < RPP) gps[t] = (base + t < cnt) ? list[base + t] : -1;
    __syncthreads();
#pragma unroll
    for (int s = 0; s < RPP; ++s) {
      const int gp = gps[s];
      if (gp >= 0)
        xs[s][t] = x[((size_t)(gp >> 12) << 20) + ((size_t)t << 12) + (gp & 4095)];
    }
    __syncthreads();

    float acc[4][RPP];
#pragma unroll
    for (int j = 0; j < 4; ++j)
#pragma unroll
      for (int s = 0; s < RPP; ++s) acc[j][s] = 0.f;

    const float* er = emb + (size_t)(t * 4) * C_DIM;
    for (int c = 0; c < C_DIM; c += 4) {
      const float4 e0 = *(const float4*)(er + c);
      const float4 e1 = *(const float4*)(er + C_DIM + c);
      const float4 e2r = *(const float4*)(er + 2 * C_DIM + c);
      const float4 e3 = *(const float4*)(er + 3 * C_DIM + c);
#pragma unroll
      for (int s = 0; s < RPP; ++s) {
        const float4 xv = *(const float4*)&xs[s][c];
        acc[0][s] = fmaf(e0.x, xv.x, acc[0][s]); acc[0][s] = fmaf(e0.y, xv.y, acc[0][s]);
        acc[0][s] = fmaf(e0.z, xv.z, acc[0][s]); acc[0][s] = fmaf(e0.w, xv.w, acc[0][s]);
        acc[1][s] = fmaf(e1.x, xv.x, acc[1][s]); acc[1][s] = fmaf(e1.y, xv.y, acc[1][s]);
        acc[1][s] = fmaf(e1.z, xv.z, acc[1][s]); acc[1][s] = fmaf(e1.w, xv.w, acc[1][s]);
        acc[2][s] = fmaf(e2r.x, xv.x, acc[2][s]); acc[2][s] = fmaf(e2r.y, xv.y, acc[2][s]);
        acc[2][s] = fmaf(e2r.z, xv.z, acc[2][s]); acc[2][s] = fmaf(e2r.w, xv.w, acc[2][s]);
        acc[3][s] = fmaf(e3.x, xv.x, acc[3][s]); acc[3][s] = fmaf(e3.y, xv.y, acc[3][s]);
        acc[3][s] = fmaf(e3.z, xv.z, acc[3][s]); acc[3][s] = fmaf(e3.w, xv.w, acc[3][s]);
      }
    }

    for (int s = 0; s < RPP; ++s) {
      float bd = 1e30f;
      int   bk = 0;
#pragma unroll
      for (int j = 0; j < 4; ++j) {
        const float sc = fmaf(-2.f, acc[j][s], e2l[j]);
        if (sc < bd) { bd = sc; bk = t * 4 + j; }     // ascending j => first idx
      }
#pragma unroll
      for (int m = 1; m < 64; m <<= 1) {
        const float od = __shfl_xor(bd, m);
        const int   oi = __shfl_xor(bk, m);
        if (od < bd || (od == bd && oi < bk)) { bd = od; bk = oi; }
      }
      if ((t & 63) == 0) { wbest[s][t >> 6] = bd; wbidx[s][t >> 6] = bk; }
    }
    __syncthreads();
    if (t < RPP && gps[t] >= 0) {
      float bd = wbest[t][0];
      int   bk = wbidx[t][0];
      for (int wv = 1; wv < 4; ++wv)
        if (wbest[t][wv] < bd || (wbest[t][wv] == bd && wbidx[t][wv] < bk)) {
          bd = wbest[t][wv]; bk = wbidx[t][wv];
        }
      idxw[gps[t]] = bk;
    }
  }
}

// ---- epilogue: gather + transposed store + loss (round-1/2 verified) ------
__global__ __launch_bounds__(256) void k_epi(const float* __restrict__ x,
                                             const float* __restrict__ emb,
                                             const int* __restrict__ idxw,
                                             float* __restrict__ out,
                                             float* __restrict__ loss_acc) {
  __shared__ int bidx_s[64];
  __shared__ float lred[4];
  const int t = threadIdx.x;
  const int tile = blockIdx.x;     // 1024 = 16 b * 64
  const int b = tile >> 6, p0 = (tile & 63) << 6;
  const float* xb = x + ((size_t)b << 20) + p0;
  float* outb = out + ((size_t)b << 20) + p0;
  if (t < 64) bidx_s[t] = idxw[((size_t)b << 12) + p0 + t] & 1023;
  __syncthreads();
  float lsum = 0.f;
#pragma unroll 4
  for (int i = 0; i < 16; ++i) {
    const int fidx = t + 256 * i;
    const int c = fidx >> 4, p4 = (fidx & 15) << 2;
    const float4 x4 = *(const float4*)&xb[((size_t)c << 12) + p4];
    const int j0 = bidx_s[p4], j1 = bidx_s[p4 + 1], j2 = bidx_s[p4 + 2], j3 = bidx_s[p4 + 3];
    const float q0 = emb[(size_t)j0 * C_DIM + c];
    const float q1 = emb[(size_t)j1 * C_DIM + c];
    const float q2 = emb[(size_t)j2 * C_DIM + c];
    const float q3 = emb[(size_t)j3 * C_DIM + c];
    const float d0 = q0 - x4.x, dd1 = q1 - x4.y, dd2 = q2 - x4.z, dd3 = q3 - x4.w;
    lsum += d0 * d0 + dd1 * dd1 + dd2 * dd2 + dd3 * dd3;
    float4 o; o.x = q0; o.y = q1; o.z = q2; o.w = q3;
    *(float4*)&outb[((size_t)c << 12) + p4] = o;
  }
  for (int off = 32; off > 0; off >>= 1) lsum += __shfl_down(lsum, off, 64);
  if ((t & 63) == 0) lred[t >> 6] = lsum;
  __syncthreads();
  if (t == 0) atomicAdd(loss_acc, lred[0] + lred[1] + lred[2] + lred[3]);
}

__global__ void k_final(const float* __restrict__ ws, float* __restrict__ out) {
  out[N_OUT] = 2.0f * ws[0] / (float)N_OUT;
}

// ================= round-1 fp32 fallback (tiny ws) ==========================
__global__ __launch_bounds__(256) void k_e2f(const float* __restrict__ emb,
                                             float* __restrict__ e2) {
  int k = blockIdx.x * 256 + threadIdx.x;
  const float* e = emb + (size_t)k * C_DIM;
  float s = 0.f;
#pragma unroll 8
  for (int c = 0; c < C_DIM; ++c) s += e[c] * e[c];
  e2[k] = s;
}

__global__ __launch_bounds__(256, 4) void k_main_r1(
    const float* __restrict__ x, const float* __restrict__ emb,
    const float* __restrict__ e2, float* __restrict__ out,
    float* __restrict__ loss_acc) {
  __shared__ float smem[64 * 64 + 64 * 64];
  float* xs = smem;
  float* es = smem + 64 * 64;
  float* red_d = smem;
  int* red_i = (int*)(smem + 64 * 16);
  int* bidx_s = (int*)(smem + 64 * 32);
  float* lred = smem + 64 * 32 + 64;
  const int t = threadIdx.x;
  const int tile = blockIdx.x;
  const int b = tile >> 6;
  const int p0 = (tile & 63) << 6;
  const float* xb = x + (size_t)b * C_DIM * HW + p0;
  const int pg = t & 15, kg = t >> 4;
  float best0 = 1e30f, best1 = 1e30f, best2 = 1e30f, best3 = 1e30f;
  int bi0 = 0, bi1 = 0, bi2 = 0, bi3 = 0;
  for (int kc = 0; kc < 16; ++kc) {
    const int k0 = kc * 64;
    float a00 = 0, a01 = 0, a02 = 0, a03 = 0, a10 = 0, a11 = 0, a12 = 0, a13 = 0;
    float a20 = 0, a21 = 0, a22 = 0, a23 = 0, a30 = 0, a31 = 0, a32 = 0, a33 = 0;
    for (int cs0 = 0; cs0 < 4; ++cs0) {
      __syncthreads();
#pragma unroll
      for (int i = 0; i < 4; ++i) {
        int fidx = t + 256 * i;
        int cs = fidx >> 4, p4 = (fidx & 15) << 2;
        *(float4*)&xs[cs * 64 + p4] = *(const float4*)&xb[(size_t)(cs0 * 64 + cs) * HW + p4];
      }
      for (int i = 0; i < 16; ++i) {
        int idx2 = t + 256 * i;
        int cs = idx2 >> 6, kk = idx2 & 63;
        es[cs * 64 + kk] = emb[(size_t)(k0 + kk) * C_DIM + cs0 * 64 + cs];
      }
      __syncthreads();
#pragma unroll 8
      for (int cs = 0; cs < 64; ++cs) {
        const float4 xv = *(const float4*)&xs[cs * 64 + (pg << 2)];
        const float4 ev = *(const float4*)&es[cs * 64 + (kg << 2)];
        a00 += xv.x * ev.x; a01 += xv.x * ev.y; a02 += xv.x * ev.z; a03 += xv.x * ev.w;
        a10 += xv.y * ev.x; a11 += xv.y * ev.y; a12 += xv.y * ev.z; a13 += xv.y * ev.w;
        a20 += xv.z * ev.x; a21 += xv.z * ev.y; a22 += xv.z * ev.z; a23 += xv.z * ev.w;
        a30 += xv.w * ev.x; a31 += xv.w * ev.y; a32 += xv.w * ev.z; a33 += xv.w * ev.w;
      }
    }
    const int kb = k0 + (kg << 2);
    const float e20 = e2[kb], e21 = e2[kb + 1], e22 = e2[kb + 2], e23 = e2[kb + 3];
    float s;
    s = e20 - 2.f * a00; if (s < best0) { best0 = s; bi0 = kb; }
    s = e21 - 2.f * a01; if (s < best0) { best0 = s; bi0 = kb + 1; }
    s = e22 - 2.f * a02; if (s < best0) { best0 = s; bi0 = kb + 2; }
    s = e23 - 2.f * a03; if (s < best0) { best0 = s; bi0 = kb + 3; }
    s = e20 - 2.f * a10; if (s < best1) { best1 = s; bi1 = kb; }
    s = e21 - 2.f * a11; if (s < best1) { best1 = s; bi1 = kb + 1; }
    s = e22 - 2.f * a12; if (s < best1) { best1 = s; bi1 = kb + 2; }
    s = e23 - 2.f * a13; if (s < best1) { best1 = s; bi1 = kb + 3; }
    s = e20 - 2.f * a20; if (s < best2) { best2 = s; bi2 = kb; }
    s = e21 - 2.f * a21; if (s < best2) { best2 = s; bi2 = kb + 1; }
    s = e22 - 2.f * a22; if (s < best2) { best2 = s; bi2 = kb + 2; }
    s = e23 - 2.f * a23; if (s < best2) { best2 = s; bi2 = kb + 3; }
    s = e20 - 2.f * a30; if (s < best3) { best3 = s; bi3 = kb; }
    s = e21 - 2.f * a31; if (s < best3) { best3 = s; bi3 = kb + 1; }
    s = e22 - 2.f * a32; if (s < best3) { best3 = s; bi3 = kb + 2; }
    s = e23 - 2.f * a33; if (s < best3) { best3 = s; bi3 = kb + 3; }
  }
  __syncthreads();
  const int prow = pg << 2;
  red_d[(prow + 0) * 16 + kg] = best0; red_i[(prow + 0) * 16 + kg] = bi0;
  red_d[(prow + 1) * 16 + kg] = best1; red_i[(prow + 1) * 16 + kg] = bi1;
  red_d[(prow + 2) * 16 + kg] = best2; red_i[(prow + 2) * 16 + kg] = bi2;
  red_d[(prow + 3) * 16 + kg] = best3; red_i[(prow + 3) * 16 + kg] = bi3;
  __syncthreads();
  if (t < 64) {
    float bd = red_d[t * 16];
    int bk = red_i[t * 16];
    for (int g = 1; g < 16; ++g) {
      float d = red_d[t * 16 + g];
      int k = red_i[t * 16 + g];
      if (d < bd || (d == bd && k < bk)) { bd = d; bk = k; }
    }
    bidx_s[t] = bk;
  }
  __syncthreads();
  float lsum = 0.f;
  float* outb = out + (size_t)b * C_DIM * HW + p0;
#pragma unroll 4
  for (int i = 0; i < 16; ++i) {
    int fidx = t + 256 * i;
    int c = fidx >> 4, p4 = (fidx & 15) << 2;
    const float4 x4 = *(const float4*)&xb[(size_t)c * HW + p4];
    const int j0 = bidx_s[p4], j1 = bidx_s[p4 + 1], j2 = bidx_s[p4 + 2], j3 = bidx_s[p4 + 3];
    const float q0 = emb[(size_t)j0 * C_DIM + c];
    const float q1 = emb[(size_t)j1 * C_DIM + c];
    const float q2 = emb[(size_t)j2 * C_DIM + c];
    const float q3 = emb[(size_t)j3 * C_DIM + c];
    const float d0 = q0 - x4.x, d1 = q1 - x4.y, d2 = q2 - x4.z, d3 = q3 - x4.w;
    lsum += d0 * d0 + d1 * d1 + d2 * d2 + d3 * d3;
    float4 o; o.x = q0; o.y = q1; o.z = q2; o.w = q3;
    *(float4*)&outb[(size_t)c * HW + p4] = o;
  }
  for (int off = 32; off > 0; off >>= 1) lsum += __shfl_down(lsum, off, 64);
  if ((t & 63) == 0) lred[t >> 6] = lsum;
  __syncthreads();
  if (t == 0) atomicAdd(loss_acc, lred[0] + lred[1] + lred[2] + lred[3]);
}

// ============================================================================
extern "C" void kernel_launch(void* const* d_in, const int* in_sizes, int n_in,
                              void* d_out, int out_size, void* d_ws, size_t ws_size,
                              hipStream_t stream) {
  const float* x = (const float*)d_in[0];
  const float* emb = (const float*)d_in[1];
  float* out = (float*)d_out;
  char* ws = (char*)d_ws;

  // ws: 0 loss | 4 cnt | 256 e2 (4 KB) | 8192 idx (256 KB)
  //     | 270336 list (64 KB) | 335872 Bp (512 KB) | end 860160
  const size_t NEED = 860160;
  if (ws_size >= NEED) {
    float* lossp = (float*)ws;
    int* cntp = (int*)(ws + 4);
    float* e2 = (float*)(ws + 256);
    int* idx = (int*)(ws + 8192);
    int* list = (int*)(ws + 270336);
    unsigned* Bp = (unsigned*)(ws + 335872);
    k_zero<<<1, 1, 0, stream>>>(lossp);
    k_e2<<<256, 256, 0, stream>>>(emb, e2);
    k_prep<<<128, 256, 0, stream>>>(emb, Bp);
    k_main<<<512, 256, 0, stream>>>(x, Bp, e2, idx, list, cntp);
    k_recheck<<<RGRID, 256, 0, stream>>>(x, emb, e2, list, cntp, idx);
    k_epi<<<1024, 256, 0, stream>>>(x, emb, idx, out, lossp);
    k_final<<<1, 1, 0, stream>>>(lossp, out);
  } else {
    float* wsf = (float*)ws;
    float* e2 = wsf + 64;
    k_zero<<<1, 1, 0, stream>>>(wsf);
    k_e2f<<<K_CODES / 256, 256, 0, stream>>>(emb, e2);
    k_main_r1<<<1024, 256, 0, stream>>>(x, emb, e2, out, wsf);
    k_final<<<1, 1, 0, stream>>>(wsf, out);
  }
}